// Round 9
// baseline (591.960 us; speedup 1.0000x reference)
//
#include <hip/hip_runtime.h>

#define D 128
#define NC 40
#define NBIN 64

typedef __attribute__((ext_vector_type(8))) short short8v;
typedef __attribute__((ext_vector_type(4))) float f32x4;

__device__ __forceinline__ unsigned short f2bf(float f) {
    unsigned u = __float_as_uint(f);
    u += 0x7fff + ((u >> 16) & 1);          // RNE
    return (unsigned short)(u >> 16);
}
__device__ __forceinline__ float bf2f(unsigned short h) {
    return __uint_as_float(((unsigned)h) << 16);
}

__device__ __forceinline__ int load_idx(const int* ei, long long pos, int is64) {
    return is64 ? ei[pos * 2] : ei[pos];
}

// per-wave int64-vs-int32 detection: check high dwords of first 64 entries
__device__ __forceinline__ int detect64(const int* __restrict__ ei) {
    int lane = threadIdx.x & 63;
    int hi = ei[lane * 2 + 1];
    return __any(hi != 0) ? 0 : 1;
}

// ---------------- graph build ----------------

// count degrees (edge blocks) + convert all weights to hi/lo bf16 planes (extra blocks)
__global__ void count_convert_kernel(const int* __restrict__ ei, int* __restrict__ deg,
                                     int E, int EB,
                                     const float* __restrict__ W1, const float* __restrict__ Wh,
                                     const float* __restrict__ Wf,
                                     unsigned short* __restrict__ Wc1, unsigned short* __restrict__ Wch0,
                                     unsigned short* __restrict__ Wch1, unsigned short* __restrict__ Wcf) {
    if (blockIdx.x < EB) {
        int is64 = detect64(ei);
        int e = blockIdx.x * 256 + threadIdx.x;
        if (e < E) {
            int d = load_idx(ei, (long long)E + e, is64);   // dst
            atomicAdd(&deg[d], 1);
        }
    } else {
        int idx = (blockIdx.x - EB) * 256 + threadIdx.x;    // 0 .. 55295
        if (idx < 49152) {
            int which = idx >> 14;                           // 0,1,2
            int j = idx & 16383;
            int nn = j >> 7, k = j & 127;
            const float* W = (which == 0) ? W1 : (which == 1) ? Wh : Wh + 16384;
            unsigned short* o = (which == 0) ? Wc1 : (which == 1) ? Wch0 : Wch1;
            float v = W[k * 128 + nn];
            unsigned short h = f2bf(v);
            o[j] = h;
            o[16384 + j] = f2bf(v - bf2f(h));
        } else if (idx < 49152 + 6144) {
            int j = idx - 49152;
            int nn = j >> 7, k = j & 127;
            float v = (nn < NC) ? Wf[k * NC + nn] : 0.f;
            unsigned short h = f2bf(v);
            Wcf[j] = h;
            Wcf[6144 + j] = f2bf(v - bf2f(h));
        }
    }
}

// phase 1: per-block (512) sums of deg
__global__ void scan1_kernel(const int* __restrict__ deg, int* __restrict__ bsum, int m) {
    int i = blockIdx.x * 512 + threadIdx.x;
    int v = (i < m) ? deg[i] : 0;
    #pragma unroll
    for (int off = 32; off; off >>= 1) v += __shfl_down(v, off, 64);
    __shared__ int ws[8];
    if ((threadIdx.x & 63) == 0) ws[threadIdx.x >> 6] = v;
    __syncthreads();
    if (threadIdx.x == 0) {
        int s = 0;
        #pragma unroll
        for (int j = 0; j < 8; ++j) s += ws[j];
        bsum[blockIdx.x] = s;
    }
}

// phase 2: inline prefix over bsum + local scan + emit rowptr/fill/dinv + degree hist
__global__ void scan3_kernel(const int* __restrict__ deg, const int* __restrict__ bsum,
                             int* __restrict__ rowptr, int* __restrict__ fill,
                             float* __restrict__ dinv, int* __restrict__ hist,
                             int n, int E, int nb) {
    int t = threadIdx.x;                       // 512
    int lane = t & 63, w = t >> 6;
    int pv = (t < nb && t < (int)blockIdx.x) ? bsum[t] : 0;
    int rs = pv;
    #pragma unroll
    for (int off = 32; off; off >>= 1) rs += __shfl_down(rs, off, 64);
    __shared__ int red[8];
    if (lane == 0) red[w] = rs;
    __syncthreads();
    int base = 0;
    #pragma unroll
    for (int j = 0; j < 8; ++j) base += red[j];
    __syncthreads();

    int i = blockIdx.x * 512 + t;
    int v = (i < n) ? deg[i] : 0;
    int s = v;
    #pragma unroll
    for (int off = 1; off < 64; off <<= 1) {
        int x = __shfl_up(s, off, 64);
        if (lane >= off) s += x;
    }
    __shared__ int wsum[8];
    if (lane == 63) wsum[w] = s;
    __syncthreads();
    int wbase = 0;
    #pragma unroll
    for (int j = 0; j < 8; ++j) if (j < w) wbase += wsum[j];
    int excl = base + wbase + s - v;
    if (i < n) {
        rowptr[i] = excl;
        fill[i]   = excl;
        dinv[i]   = rsqrtf((float)(v + 1));   // +1 self loop
        atomicAdd(&hist[v < NBIN ? v : NBIN - 1], 1);
    }
    if (i == 0) rowptr[n] = E;
}

// exclusive scan of 64-bin histogram -> cursor
__global__ void binscan_kernel(const int* __restrict__ hist, int* __restrict__ cursor) {
    int t = threadIdx.x;        // 64
    int v = hist[t];
    int s = v;
    #pragma unroll
    for (int off = 1; off < 64; off <<= 1) {
        int x = __shfl_up(s, off, 64);
        if (t >= off) s += x;
    }
    cursor[t] = s - v;
}

// scatter node ids into degree-sorted order
__global__ void permute_kernel(const int* __restrict__ deg, int* __restrict__ cursor,
                               int* __restrict__ perm, int n) {
    int i = blockIdx.x * 256 + threadIdx.x;
    if (i >= n) return;
    int v = deg[i];
    int pos = atomicAdd(&cursor[v < NBIN ? v : NBIN - 1], 1);
    perm[pos] = i;
}

// scatter edge -> CSR, packing {src, dinv[src]}
__global__ void scatter_kernel(const int* __restrict__ ei, int* __restrict__ fill,
                               const float* __restrict__ dinv, int2* __restrict__ col2, int E) {
    int is64 = detect64(ei);
    int e = blockIdx.x * 256 + threadIdx.x;
    if (e >= E) return;
    int s = load_idx(ei, (long long)e, is64);
    int d = load_idx(ei, (long long)E + e, is64);
    int pos = atomicAdd(&fill[d], 1);
    col2[pos] = make_int2(s, __float_as_int(dinv[s]));
}

// ---------------- fused layer: out = relu( agg(h) @ W + b ) ----------------
// 512 threads = 16 nodes x 32 lanes. Nodes come from the degree-sorted perm,
// so all 16 nodes in a block have ~equal degree -> the pre-MFMA barrier costs
// ~0 (r8's unbalanced blocks ran at max-of-16 degree, +35%).
__launch_bounds__(512)
__global__ void fused_layer_kernel(const float4* __restrict__ h4,
                                   const unsigned short* __restrict__ Wcvt,  // [128n][128k] hi,lo
                                   const float* __restrict__ bias,
                                   const float* __restrict__ dinv,
                                   const int* __restrict__ rowptr, const int2* __restrict__ col2,
                                   const int* __restrict__ perm,
                                   float* __restrict__ out, int n) {
    __shared__ unsigned short Ah[16 * 128];    // 4KB
    __shared__ unsigned short Al[16 * 128];    // 4KB
    __shared__ int pnodes[16];
    int t = threadIdx.x;
    int g = t >> 5, l = t & 31;                // node group (16), lane-in-group (32)
    int idx = blockIdx.x * 16 + g;
    int nd = perm[(idx < n) ? idx : 0];
    if (l == 0) pnodes[g] = (idx < n) ? nd : -1;
    float dn = dinv[nd];
    size_t rowbase = (size_t)nd * 32;

    float4 hv = h4[rowbase + l];
    float4 acc;
    acc.x = hv.x * dn; acc.y = hv.y * dn; acc.z = hv.z * dn; acc.w = hv.w * dn;
    int e = rowptr[nd], e1 = rowptr[nd + 1];
    for (; e + 8 <= e1; e += 8) {
        int2 c[8];
        #pragma unroll
        for (int j = 0; j < 8; ++j) c[j] = col2[e + j];
        float4 v[8];
        #pragma unroll
        for (int j = 0; j < 8; ++j) v[j] = h4[(size_t)c[j].x * 32 + l];
        #pragma unroll
        for (int j = 0; j < 8; ++j) {
            float ds = __int_as_float(c[j].y);
            acc.x += v[j].x * ds; acc.y += v[j].y * ds;
            acc.z += v[j].z * ds; acc.w += v[j].w * ds;
        }
    }
    for (; e + 4 <= e1; e += 4) {
        int2 c[4];
        #pragma unroll
        for (int j = 0; j < 4; ++j) c[j] = col2[e + j];
        float4 v[4];
        #pragma unroll
        for (int j = 0; j < 4; ++j) v[j] = h4[(size_t)c[j].x * 32 + l];
        #pragma unroll
        for (int j = 0; j < 4; ++j) {
            float ds = __int_as_float(c[j].y);
            acc.x += v[j].x * ds; acc.y += v[j].y * ds;
            acc.z += v[j].z * ds; acc.w += v[j].w * ds;
        }
    }
    for (; e < e1; ++e) {
        int2 c = col2[e];
        float ds = __int_as_float(c.y);
        float4 v = h4[(size_t)c.x * 32 + l];
        acc.x += v.x * ds; acc.y += v.y * ds; acc.z += v.z * ds; acc.w += v.w * ds;
    }
    acc.x *= dn; acc.y *= dn; acc.z *= dn; acc.w *= dn;   // bias after transform

    // split & stage: lane l holds k-elements 4l..4l+3 of tile row g
    {
        ushort4 hi, lo;
        hi.x = f2bf(acc.x); lo.x = f2bf(acc.x - bf2f(hi.x));
        hi.y = f2bf(acc.y); lo.y = f2bf(acc.y - bf2f(hi.y));
        hi.z = f2bf(acc.z); lo.z = f2bf(acc.z - bf2f(hi.z));
        hi.w = f2bf(acc.w); lo.w = f2bf(acc.w - bf2f(hi.w));
        int off = (g << 8) + ((l << 3) ^ ((g & 7) << 4));   // bijective in-row swizzle
        *(ushort4*)((char*)Ah + off) = hi;
        *(ushort4*)((char*)Al + off) = lo;
    }
    __syncthreads();

    // MFMA: 8 waves x 16 cols each, M=16 rows (the block's 16 nodes)
    int l64 = t & 63, wv = t >> 6;
    int lr = l64 & 15, lh = l64 >> 4;
    int n0 = wv * 16;
    const unsigned short* Whi = Wcvt;
    const unsigned short* Wlo = Wcvt + 128 * 128;
    f32x4 o = (f32x4){0.f, 0.f, 0.f, 0.f};
    #pragma unroll
    for (int ks = 0; ks < 4; ++ks) {
        int aoff = (lr << 8) + (((ks << 6) + (lh << 4)) ^ ((lr & 7) << 4));
        short8v ah = *(short8v*)((char*)Ah + aoff);
        short8v al = *(short8v*)((char*)Al + aoff);
        int c0 = (n0 + lr) * 128 + ks * 32 + lh * 8;
        short8v bh = *(const short8v*)&Whi[c0];
        short8v bl = *(const short8v*)&Wlo[c0];
        o = __builtin_amdgcn_mfma_f32_16x16x32_bf16(ah, bh, o, 0, 0, 0);
        o = __builtin_amdgcn_mfma_f32_16x16x32_bf16(ah, bl, o, 0, 0, 0);
        o = __builtin_amdgcn_mfma_f32_16x16x32_bf16(al, bh, o, 0, 0, 0);
    }
    // epilogue: bias + relu; D layout col=lane&15, row=(lane>>4)*4+r -> out[perm row]
    float bv = bias[n0 + lr];
    #pragma unroll
    for (int r = 0; r < 4; ++r) {
        int pr = pnodes[lh * 4 + r];
        if (pr >= 0) out[(size_t)pr * 128 + n0 + lr] = fmaxf(o[r] + bv, 0.f);
    }
}

// ---------------- MFMA final layer  C[M x 40] = A[M x 128] @ Wf + bf ----------------
__launch_bounds__(256)
__global__ void final_mfma_kernel(const float* __restrict__ A, const unsigned short* __restrict__ Wcvt,
                                  const float* __restrict__ bf, float* __restrict__ C, int M) {
    __shared__ unsigned short Ah[64 * 128];
    __shared__ unsigned short Al[64 * 128];
    int t = threadIdx.x;
    int l = t & 63, w = t >> 6;
    int lr = l & 15, lh = l >> 4;

    const unsigned short* Whi = Wcvt;            // [48n][128k]
    const unsigned short* Wlo = Wcvt + 48 * 128;
    short8v bhi[3][4], blo[3][4];
    #pragma unroll
    for (int nt = 0; nt < 3; ++nt) {
        int n = nt * 16 + lr;
        #pragma unroll
        for (int ks = 0; ks < 4; ++ks) {
            bhi[nt][ks] = *(const short8v*)&Whi[n * 128 + ks * 32 + lh * 8];
            blo[nt][ks] = *(const short8v*)&Wlo[n * 128 + ks * 32 + lh * 8];
        }
    }

    int row0 = blockIdx.x * 64;
    #pragma unroll
    for (int c = 0; c < 4; ++c) {
        int chunk = c * 256 + t;
        int r  = chunk >> 4;
        int kc = chunk & 15;
        int gr = row0 + r; if (gr >= M) gr = M - 1;
        float4 a0 = *(const float4*)&A[(size_t)gr * 128 + kc * 8];
        float4 a1 = *(const float4*)&A[(size_t)gr * 128 + kc * 8 + 4];
        float av[8] = {a0.x, a0.y, a0.z, a0.w, a1.x, a1.y, a1.z, a1.w};
        short8v hv, lv;
        #pragma unroll
        for (int j = 0; j < 8; ++j) {
            unsigned short hi = f2bf(av[j]);
            hv[j] = (short)hi;
            lv[j] = (short)f2bf(av[j] - bf2f(hi));
        }
        int off = (r << 8) + ((kc << 4) ^ ((r & 7) << 4));
        *(short8v*)((char*)Ah + off) = hv;
        *(short8v*)((char*)Al + off) = lv;
    }
    __syncthreads();

    f32x4 acc[3];
    #pragma unroll
    for (int nt = 0; nt < 3; ++nt) acc[nt] = (f32x4){0.f, 0.f, 0.f, 0.f};
    int row = w * 16 + lr;
    #pragma unroll
    for (int ks = 0; ks < 4; ++ks) {
        int off = (row << 8) + (((ks << 6) + (lh << 4)) ^ ((row & 7) << 4));
        short8v ah = *(short8v*)((char*)Ah + off);
        short8v al = *(short8v*)((char*)Al + off);
        #pragma unroll
        for (int nt = 0; nt < 3; ++nt) {
            acc[nt] = __builtin_amdgcn_mfma_f32_16x16x32_bf16(ah, bhi[nt][ks], acc[nt], 0, 0, 0);
            acc[nt] = __builtin_amdgcn_mfma_f32_16x16x32_bf16(ah, blo[nt][ks], acc[nt], 0, 0, 0);
            acc[nt] = __builtin_amdgcn_mfma_f32_16x16x32_bf16(al, bhi[nt][ks], acc[nt], 0, 0, 0);
        }
    }
    #pragma unroll
    for (int nt = 0; nt < 3; ++nt) {
        int col = nt * 16 + lr;
        #pragma unroll
        for (int r = 0; r < 4; ++r) {
            int ro = row0 + w * 16 + lh * 4 + r;
            if (col < NC && ro < M) C[(size_t)ro * NC + col] = acc[nt][r] + bf[col];
        }
    }
}

extern "C" void kernel_launch(void* const* d_in, const int* in_sizes, int n_in,
                              void* d_out, int out_size, void* d_ws, size_t ws_size,
                              hipStream_t stream) {
    const float* x  = (const float*)d_in[0];
    const int*   ei = (const int*)d_in[1];
    const float* W1 = (const float*)d_in[2];
    const float* b1 = (const float*)d_in[3];
    const float* Wh = (const float*)d_in[4];
    const float* bh = (const float*)d_in[5];
    const float* Wf = (const float*)d_in[6];
    const float* bf = (const float*)d_in[7];
    float* out = (float*)d_out;

    int n = in_sizes[0] / D;    // 50000
    int E = in_sizes[1] / 2;    // 800000

    char* ws = (char*)d_ws;
    size_t off = 0;
    auto alloc = [&](size_t bytes) {
        void* p = ws + off;
        off = (off + bytes + 255) & ~(size_t)255;
        return p;
    };
    float* B0     = (float*)alloc((size_t)n * D * 4);
    float* B1     = (float*)alloc((size_t)n * D * 4);
    int*   deg    = (int*)alloc((size_t)n * 4);
    int*   rowptr = (int*)alloc((size_t)(n + 1) * 4);
    int*   fill   = (int*)alloc((size_t)n * 4);
    int2*  col2   = (int2*)alloc((size_t)E * 8);
    float* dinv   = (float*)alloc((size_t)n * 4);
    int*   bsum   = (int*)alloc(1024 * 4);
    int*   hist   = (int*)alloc(NBIN * 4);
    int*   cursor = (int*)alloc(NBIN * 4);
    int*   perm   = (int*)alloc((size_t)n * 4);
    unsigned short* Wc1  = (unsigned short*)alloc(2 * 128 * 128 * 2);
    unsigned short* Wch0 = (unsigned short*)alloc(2 * 128 * 128 * 2);
    unsigned short* Wch1 = (unsigned short*)alloc(2 * 128 * 128 * 2);
    unsigned short* Wcf  = (unsigned short*)alloc(2 * 48 * 128 * 2);

    int EB = (E + 255) / 256;             // edge blocks
    int CB = (49152 + 6144 + 255) / 256;  // convert blocks
    int nb = (n + 511) / 512;             // 98

    hipMemsetAsync(deg, 0, (size_t)n * 4, stream);
    hipMemsetAsync(hist, 0, NBIN * 4, stream);
    count_convert_kernel<<<EB + CB, 256, 0, stream>>>(ei, deg, E, EB, W1, Wh, Wf, Wc1, Wch0, Wch1, Wcf);
    scan1_kernel<<<nb, 512, 0, stream>>>(deg, bsum, n);
    scan3_kernel<<<nb, 512, 0, stream>>>(deg, bsum, rowptr, fill, dinv, hist, n, E, nb);
    binscan_kernel<<<1, 64, 0, stream>>>(hist, cursor);
    permute_kernel<<<(n + 255) / 256, 256, 0, stream>>>(deg, cursor, perm, n);
    scatter_kernel<<<EB, 256, 0, stream>>>(ei, fill, dinv, col2, E);

    int fgrid = (n + 15) / 16;

    fused_layer_kernel<<<fgrid, 512, 0, stream>>>((const float4*)x, Wc1, b1, dinv, rowptr, col2, perm, B0, n);
    fused_layer_kernel<<<fgrid, 512, 0, stream>>>((const float4*)B0, Wch0, bh, dinv, rowptr, col2, perm, B1, n);
    fused_layer_kernel<<<fgrid, 512, 0, stream>>>((const float4*)B1, Wch1, bh + D, dinv, rowptr, col2, perm, B0, n);
    final_mfma_kernel<<<(n + 63) / 64, 256, 0, stream>>>(B0, Wcf, bf, out, n);
}

// Round 10
// 331.891 us; speedup vs baseline: 1.7836x; 1.7836x over previous
//
#include <hip/hip_runtime.h>

#define D 128
#define NC 40
#define NBIN 64

typedef __attribute__((ext_vector_type(8))) short short8v;
typedef __attribute__((ext_vector_type(4))) float f32x4;

__device__ __forceinline__ unsigned short f2bf(float f) {
    unsigned u = __float_as_uint(f);
    u += 0x7fff + ((u >> 16) & 1);          // RNE
    return (unsigned short)(u >> 16);
}
__device__ __forceinline__ float bf2f(unsigned short h) {
    return __uint_as_float(((unsigned)h) << 16);
}

__device__ __forceinline__ int load_idx(const int* ei, long long pos, int is64) {
    return is64 ? ei[pos * 2] : ei[pos];
}

// per-wave int64-vs-int32 detection: check high dwords of first 64 entries
__device__ __forceinline__ int detect64(const int* __restrict__ ei) {
    int lane = threadIdx.x & 63;
    int hi = ei[lane * 2 + 1];
    return __any(hi != 0) ? 0 : 1;
}

// ---------------- graph build ----------------

// count degrees (edge blocks) + convert all weights to hi/lo bf16 planes (extra blocks)
__global__ void count_convert_kernel(const int* __restrict__ ei, int* __restrict__ deg,
                                     int E, int EB,
                                     const float* __restrict__ W1, const float* __restrict__ Wh,
                                     const float* __restrict__ Wf,
                                     unsigned short* __restrict__ Wc1, unsigned short* __restrict__ Wch0,
                                     unsigned short* __restrict__ Wch1, unsigned short* __restrict__ Wcf) {
    if (blockIdx.x < EB) {
        int is64 = detect64(ei);
        int e = blockIdx.x * 256 + threadIdx.x;
        if (e < E) {
            int d = load_idx(ei, (long long)E + e, is64);   // dst
            atomicAdd(&deg[d], 1);
        }
    } else {
        int idx = (blockIdx.x - EB) * 256 + threadIdx.x;    // 0 .. 55295
        if (idx < 49152) {
            int which = idx >> 14;                           // 0,1,2
            int j = idx & 16383;
            int nn = j >> 7, k = j & 127;
            const float* W = (which == 0) ? W1 : (which == 1) ? Wh : Wh + 16384;
            unsigned short* o = (which == 0) ? Wc1 : (which == 1) ? Wch0 : Wch1;
            float v = W[k * 128 + nn];
            unsigned short h = f2bf(v);
            o[j] = h;
            o[16384 + j] = f2bf(v - bf2f(h));
        } else if (idx < 49152 + 6144) {
            int j = idx - 49152;
            int nn = j >> 7, k = j & 127;
            float v = (nn < NC) ? Wf[k * NC + nn] : 0.f;
            unsigned short h = f2bf(v);
            Wcf[j] = h;
            Wcf[6144 + j] = f2bf(v - bf2f(h));
        }
    }
}

// phase 1: per-block (512) sums of deg
__global__ void scan1_kernel(const int* __restrict__ deg, int* __restrict__ bsum, int m) {
    int i = blockIdx.x * 512 + threadIdx.x;
    int v = (i < m) ? deg[i] : 0;
    #pragma unroll
    for (int off = 32; off; off >>= 1) v += __shfl_down(v, off, 64);
    __shared__ int ws[8];
    if ((threadIdx.x & 63) == 0) ws[threadIdx.x >> 6] = v;
    __syncthreads();
    if (threadIdx.x == 0) {
        int s = 0;
        #pragma unroll
        for (int j = 0; j < 8; ++j) s += ws[j];
        bsum[blockIdx.x] = s;
    }
}

// phase 2: inline prefix over bsum + local scan + emit rowptr/fill/dinv
__global__ void scan3_kernel(const int* __restrict__ deg, const int* __restrict__ bsum,
                             int* __restrict__ rowptr, int* __restrict__ fill,
                             float* __restrict__ dinv, int n, int E, int nb) {
    int t = threadIdx.x;                       // 512
    int lane = t & 63, w = t >> 6;
    int pv = (t < nb && t < (int)blockIdx.x) ? bsum[t] : 0;
    int rs = pv;
    #pragma unroll
    for (int off = 32; off; off >>= 1) rs += __shfl_down(rs, off, 64);
    __shared__ int red[8];
    if (lane == 0) red[w] = rs;
    __syncthreads();
    int base = 0;
    #pragma unroll
    for (int j = 0; j < 8; ++j) base += red[j];
    __syncthreads();

    int i = blockIdx.x * 512 + t;
    int v = (i < n) ? deg[i] : 0;
    int s = v;
    #pragma unroll
    for (int off = 1; off < 64; off <<= 1) {
        int x = __shfl_up(s, off, 64);
        if (lane >= off) s += x;
    }
    __shared__ int wsum[8];
    if (lane == 63) wsum[w] = s;
    __syncthreads();
    int wbase = 0;
    #pragma unroll
    for (int j = 0; j < 8; ++j) if (j < w) wbase += wsum[j];
    int excl = base + wbase + s - v;
    if (i < n) {
        rowptr[i] = excl;
        fill[i]   = excl;
        dinv[i]   = rsqrtf((float)(v + 1));   // +1 self loop
    }
    if (i == 0) rowptr[n] = E;
}

// ---- contention-free counting sort by degree, DESCENDING (heavy blocks first) ----
// A: per-block LDS histogram -> ghist[bin][blk]
__global__ void sortA_kernel(const int* __restrict__ deg, int* __restrict__ ghist,
                             int n, int nsb) {
    __shared__ int lhist[NBIN];
    int t = threadIdx.x;           // 512
    if (t < NBIN) lhist[t] = 0;
    __syncthreads();
    int i = blockIdx.x * 512 + t;
    if (i < n) {
        int v = deg[i];
        int b = v < NBIN ? v : NBIN - 1;
        atomicAdd(&lhist[(NBIN - 1) - b], 1);   // descending degree order
    }
    __syncthreads();
    if (t < NBIN) ghist[t * nsb + blockIdx.x] = lhist[t];
}

// B: single-block exclusive scan over m = NBIN*nsb entries (in place)
__global__ void sortB_kernel(int* __restrict__ ghist, int m) {
    __shared__ int wsum[16];
    int t = threadIdx.x;            // 1024
    int lane = t & 63, w = t >> 6;
    int base = 0;
    int nchunk = (m + 1023) >> 10;
    for (int c = 0; c < nchunk; ++c) {
        int i = (c << 10) + t;
        int v = (i < m) ? ghist[i] : 0;
        int s = v;
        #pragma unroll
        for (int off = 1; off < 64; off <<= 1) {
            int x = __shfl_up(s, off, 64);
            if (lane >= off) s += x;
        }
        if (lane == 63) wsum[w] = s;
        __syncthreads();
        int wbase = 0, total = 0;
        #pragma unroll
        for (int j = 0; j < 16; ++j) {
            int wj = wsum[j];
            if (j < w) wbase += wj;
            total += wj;
        }
        if (i < m) ghist[i] = base + wbase + s - v;
        __syncthreads();
        base += total;
    }
}

// C: emit perm via LDS cursors seeded from the scanned offsets
__global__ void sortC_kernel(const int* __restrict__ deg, const int* __restrict__ goff,
                             int* __restrict__ perm, int n, int nsb) {
    __shared__ int lcur[NBIN];
    int t = threadIdx.x;           // 512
    if (t < NBIN) lcur[t] = goff[t * nsb + blockIdx.x];
    __syncthreads();
    int i = blockIdx.x * 512 + t;
    if (i < n) {
        int v = deg[i];
        int b = v < NBIN ? v : NBIN - 1;
        int pos = atomicAdd(&lcur[(NBIN - 1) - b], 1);
        perm[pos] = i;
    }
}

// scatter edge -> CSR, packing {src, dinv[src]}
__global__ void scatter_kernel(const int* __restrict__ ei, int* __restrict__ fill,
                               const float* __restrict__ dinv, int2* __restrict__ col2, int E) {
    int is64 = detect64(ei);
    int e = blockIdx.x * 256 + threadIdx.x;
    if (e >= E) return;
    int s = load_idx(ei, (long long)e, is64);
    int d = load_idx(ei, (long long)E + e, is64);
    int pos = atomicAdd(&fill[d], 1);
    col2[pos] = make_int2(s, __float_as_int(dinv[s]));
}

// ---------------- fused layer: out = relu( agg(h) @ W + b ) ----------------
// 512 threads = 16 nodes x 32 lanes, nodes from the DESCENDING degree-sorted
// perm: all 16 nodes in a block have ~equal degree (barrier cost ~0) and heavy
// blocks launch first (no grid tail).
__launch_bounds__(512)
__global__ void fused_layer_kernel(const float4* __restrict__ h4,
                                   const unsigned short* __restrict__ Wcvt,  // [128n][128k] hi,lo
                                   const float* __restrict__ bias,
                                   const float* __restrict__ dinv,
                                   const int* __restrict__ rowptr, const int2* __restrict__ col2,
                                   const int* __restrict__ perm,
                                   float* __restrict__ out, int n) {
    __shared__ unsigned short Ah[16 * 128];    // 4KB
    __shared__ unsigned short Al[16 * 128];    // 4KB
    __shared__ int pnodes[16];
    int t = threadIdx.x;
    int g = t >> 5, l = t & 31;                // node group (16), lane-in-group (32)
    int idx = blockIdx.x * 16 + g;
    int nd = perm[(idx < n) ? idx : 0];
    if (l == 0) pnodes[g] = (idx < n) ? nd : -1;
    float dn = dinv[nd];
    size_t rowbase = (size_t)nd * 32;

    float4 hv = h4[rowbase + l];
    float4 acc;
    acc.x = hv.x * dn; acc.y = hv.y * dn; acc.z = hv.z * dn; acc.w = hv.w * dn;
    int e = rowptr[nd], e1 = rowptr[nd + 1];
    for (; e + 8 <= e1; e += 8) {
        int2 c[8];
        #pragma unroll
        for (int j = 0; j < 8; ++j) c[j] = col2[e + j];
        float4 v[8];
        #pragma unroll
        for (int j = 0; j < 8; ++j) v[j] = h4[(size_t)c[j].x * 32 + l];
        #pragma unroll
        for (int j = 0; j < 8; ++j) {
            float ds = __int_as_float(c[j].y);
            acc.x += v[j].x * ds; acc.y += v[j].y * ds;
            acc.z += v[j].z * ds; acc.w += v[j].w * ds;
        }
    }
    for (; e + 4 <= e1; e += 4) {
        int2 c[4];
        #pragma unroll
        for (int j = 0; j < 4; ++j) c[j] = col2[e + j];
        float4 v[4];
        #pragma unroll
        for (int j = 0; j < 4; ++j) v[j] = h4[(size_t)c[j].x * 32 + l];
        #pragma unroll
        for (int j = 0; j < 4; ++j) {
            float ds = __int_as_float(c[j].y);
            acc.x += v[j].x * ds; acc.y += v[j].y * ds;
            acc.z += v[j].z * ds; acc.w += v[j].w * ds;
        }
    }
    for (; e < e1; ++e) {
        int2 c = col2[e];
        float ds = __int_as_float(c.y);
        float4 v = h4[(size_t)c.x * 32 + l];
        acc.x += v.x * ds; acc.y += v.y * ds; acc.z += v.z * ds; acc.w += v.w * ds;
    }
    acc.x *= dn; acc.y *= dn; acc.z *= dn; acc.w *= dn;   // bias after transform

    // split & stage: lane l holds k-elements 4l..4l+3 of tile row g
    {
        ushort4 hi, lo;
        hi.x = f2bf(acc.x); lo.x = f2bf(acc.x - bf2f(hi.x));
        hi.y = f2bf(acc.y); lo.y = f2bf(acc.y - bf2f(hi.y));
        hi.z = f2bf(acc.z); lo.z = f2bf(acc.z - bf2f(hi.z));
        hi.w = f2bf(acc.w); lo.w = f2bf(acc.w - bf2f(hi.w));
        int off = (g << 8) + ((l << 3) ^ ((g & 7) << 4));   // bijective in-row swizzle
        *(ushort4*)((char*)Ah + off) = hi;
        *(ushort4*)((char*)Al + off) = lo;
    }
    __syncthreads();

    // MFMA: 8 waves x 16 cols each, M=16 rows (the block's 16 nodes)
    int l64 = t & 63, wv = t >> 6;
    int lr = l64 & 15, lh = l64 >> 4;
    int n0 = wv * 16;
    const unsigned short* Whi = Wcvt;
    const unsigned short* Wlo = Wcvt + 128 * 128;
    f32x4 o = (f32x4){0.f, 0.f, 0.f, 0.f};
    #pragma unroll
    for (int ks = 0; ks < 4; ++ks) {
        int aoff = (lr << 8) + (((ks << 6) + (lh << 4)) ^ ((lr & 7) << 4));
        short8v ah = *(short8v*)((char*)Ah + aoff);
        short8v al = *(short8v*)((char*)Al + aoff);
        int c0 = (n0 + lr) * 128 + ks * 32 + lh * 8;
        short8v bh = *(const short8v*)&Whi[c0];
        short8v bl = *(const short8v*)&Wlo[c0];
        o = __builtin_amdgcn_mfma_f32_16x16x32_bf16(ah, bh, o, 0, 0, 0);
        o = __builtin_amdgcn_mfma_f32_16x16x32_bf16(ah, bl, o, 0, 0, 0);
        o = __builtin_amdgcn_mfma_f32_16x16x32_bf16(al, bh, o, 0, 0, 0);
    }
    // epilogue: bias + relu; D layout col=lane&15, row=(lane>>4)*4+r -> out[perm row]
    float bv = bias[n0 + lr];
    #pragma unroll
    for (int r = 0; r < 4; ++r) {
        int pr = pnodes[lh * 4 + r];
        if (pr >= 0) out[(size_t)pr * 128 + n0 + lr] = fmaxf(o[r] + bv, 0.f);
    }
}

// ---------------- MFMA final layer  C[M x 40] = A[M x 128] @ Wf + bf ----------------
__launch_bounds__(256)
__global__ void final_mfma_kernel(const float* __restrict__ A, const unsigned short* __restrict__ Wcvt,
                                  const float* __restrict__ bf, float* __restrict__ C, int M) {
    __shared__ unsigned short Ah[64 * 128];
    __shared__ unsigned short Al[64 * 128];
    int t = threadIdx.x;
    int l = t & 63, w = t >> 6;
    int lr = l & 15, lh = l >> 4;

    const unsigned short* Whi = Wcvt;            // [48n][128k]
    const unsigned short* Wlo = Wcvt + 48 * 128;
    short8v bhi[3][4], blo[3][4];
    #pragma unroll
    for (int nt = 0; nt < 3; ++nt) {
        int n = nt * 16 + lr;
        #pragma unroll
        for (int ks = 0; ks < 4; ++ks) {
            bhi[nt][ks] = *(const short8v*)&Whi[n * 128 + ks * 32 + lh * 8];
            blo[nt][ks] = *(const short8v*)&Wlo[n * 128 + ks * 32 + lh * 8];
        }
    }

    int row0 = blockIdx.x * 64;
    #pragma unroll
    for (int c = 0; c < 4; ++c) {
        int chunk = c * 256 + t;
        int r  = chunk >> 4;
        int kc = chunk & 15;
        int gr = row0 + r; if (gr >= M) gr = M - 1;
        float4 a0 = *(const float4*)&A[(size_t)gr * 128 + kc * 8];
        float4 a1 = *(const float4*)&A[(size_t)gr * 128 + kc * 8 + 4];
        float av[8] = {a0.x, a0.y, a0.z, a0.w, a1.x, a1.y, a1.z, a1.w};
        short8v hv, lv;
        #pragma unroll
        for (int j = 0; j < 8; ++j) {
            unsigned short hi = f2bf(av[j]);
            hv[j] = (short)hi;
            lv[j] = (short)f2bf(av[j] - bf2f(hi));
        }
        int off = (r << 8) + ((kc << 4) ^ ((r & 7) << 4));
        *(short8v*)((char*)Ah + off) = hv;
        *(short8v*)((char*)Al + off) = lv;
    }
    __syncthreads();

    f32x4 acc[3];
    #pragma unroll
    for (int nt = 0; nt < 3; ++nt) acc[nt] = (f32x4){0.f, 0.f, 0.f, 0.f};
    int row = w * 16 + lr;
    #pragma unroll
    for (int ks = 0; ks < 4; ++ks) {
        int off = (row << 8) + (((ks << 6) + (lh << 4)) ^ ((row & 7) << 4));
        short8v ah = *(short8v*)((char*)Ah + off);
        short8v al = *(short8v*)((char*)Al + off);
        #pragma unroll
        for (int nt = 0; nt < 3; ++nt) {
            acc[nt] = __builtin_amdgcn_mfma_f32_16x16x32_bf16(ah, bhi[nt][ks], acc[nt], 0, 0, 0);
            acc[nt] = __builtin_amdgcn_mfma_f32_16x16x32_bf16(ah, blo[nt][ks], acc[nt], 0, 0, 0);
            acc[nt] = __builtin_amdgcn_mfma_f32_16x16x32_bf16(al, bhi[nt][ks], acc[nt], 0, 0, 0);
        }
    }
    #pragma unroll
    for (int nt = 0; nt < 3; ++nt) {
        int col = nt * 16 + lr;
        #pragma unroll
        for (int r = 0; r < 4; ++r) {
            int ro = row0 + w * 16 + lh * 4 + r;
            if (col < NC && ro < M) C[(size_t)ro * NC + col] = acc[nt][r] + bf[col];
        }
    }
}

extern "C" void kernel_launch(void* const* d_in, const int* in_sizes, int n_in,
                              void* d_out, int out_size, void* d_ws, size_t ws_size,
                              hipStream_t stream) {
    const float* x  = (const float*)d_in[0];
    const int*   ei = (const int*)d_in[1];
    const float* W1 = (const float*)d_in[2];
    const float* b1 = (const float*)d_in[3];
    const float* Wh = (const float*)d_in[4];
    const float* bh = (const float*)d_in[5];
    const float* Wf = (const float*)d_in[6];
    const float* bf = (const float*)d_in[7];
    float* out = (float*)d_out;

    int n = in_sizes[0] / D;    // 50000
    int E = in_sizes[1] / 2;    // 800000

    char* ws = (char*)d_ws;
    size_t off = 0;
    auto alloc = [&](size_t bytes) {
        void* p = ws + off;
        off = (off + bytes + 255) & ~(size_t)255;
        return p;
    };
    float* B0     = (float*)alloc((size_t)n * D * 4);
    float* B1     = (float*)alloc((size_t)n * D * 4);
    int*   deg    = (int*)alloc((size_t)n * 4);
    int*   rowptr = (int*)alloc((size_t)(n + 1) * 4);
    int*   fill   = (int*)alloc((size_t)n * 4);
    int2*  col2   = (int2*)alloc((size_t)E * 8);
    float* dinv   = (float*)alloc((size_t)n * 4);
    int*   bsum   = (int*)alloc(1024 * 4);
    int*   perm   = (int*)alloc((size_t)n * 4);
    unsigned short* Wc1  = (unsigned short*)alloc(2 * 128 * 128 * 2);
    unsigned short* Wch0 = (unsigned short*)alloc(2 * 128 * 128 * 2);
    unsigned short* Wch1 = (unsigned short*)alloc(2 * 128 * 128 * 2);
    unsigned short* Wcf  = (unsigned short*)alloc(2 * 48 * 128 * 2);

    int EB = (E + 255) / 256;             // edge blocks
    int CB = (49152 + 6144 + 255) / 256;  // convert blocks
    int nb = (n + 511) / 512;             // 98 (sort blocks too)
    int*   ghist  = (int*)alloc((size_t)NBIN * nb * 4);

    hipMemsetAsync(deg, 0, (size_t)n * 4, stream);
    count_convert_kernel<<<EB + CB, 256, 0, stream>>>(ei, deg, E, EB, W1, Wh, Wf, Wc1, Wch0, Wch1, Wcf);
    scan1_kernel<<<nb, 512, 0, stream>>>(deg, bsum, n);
    scan3_kernel<<<nb, 512, 0, stream>>>(deg, bsum, rowptr, fill, dinv, n, E, nb);
    sortA_kernel<<<nb, 512, 0, stream>>>(deg, ghist, n, nb);
    sortB_kernel<<<1, 1024, 0, stream>>>(ghist, NBIN * nb);
    sortC_kernel<<<nb, 512, 0, stream>>>(deg, ghist, perm, n, nb);
    scatter_kernel<<<EB, 256, 0, stream>>>(ei, fill, dinv, col2, E);

    int fgrid = (n + 15) / 16;

    fused_layer_kernel<<<fgrid, 512, 0, stream>>>((const float4*)x, Wc1, b1, dinv, rowptr, col2, perm, B0, n);
    fused_layer_kernel<<<fgrid, 512, 0, stream>>>((const float4*)B0, Wch0, bh, dinv, rowptr, col2, perm, B1, n);
    fused_layer_kernel<<<fgrid, 512, 0, stream>>>((const float4*)B1, Wch1, bh + D, dinv, rowptr, col2, perm, B0, n);
    final_mfma_kernel<<<(n + 63) / 64, 256, 0, stream>>>(B0, Wcf, bf, out, n);
}